// Round 2
// baseline (191151.550 us; speedup 1.0000x reference)
//
#include <hip/hip_runtime.h>
#include <math.h>

#define TT 512
#define BB 64
#define II 512
#define HH 1024
#define OO 512
#define KK 1536   // I + H

#define GRID 256
#define NTHR 512

__device__ __forceinline__ float sigmoidf_(float v) {
    return 1.0f / (1.0f + __expf(-v));
}

// ---- write-through (LLC) store for mutable shared state ----
// Stores must reach the Infinity Cache so other XCDs can see them after the
// barrier; loads are NORMAL cached loads (L1+L2), made safe by the agent-scope
// acquire fence (buffer_inv) issued inside gbar().
__device__ __forceinline__ void st_sys(float* p, float v) {
    asm volatile("global_store_dword %0, %1, off sc0 sc1"
                 :: "v"(p), "v"(v) : "memory");
}

// Grid barrier: release (drain write-through stores) -> counter -> acquire
// (L1+L2 invalidate so cached loads see fresh LLC data).
__device__ __forceinline__ void gbar(unsigned* ctr, unsigned target, int tid)
{
    asm volatile("s_waitcnt vmcnt(0)" ::: "memory");
    __syncthreads();
    if (tid == 0) {
        __hip_atomic_fetch_add(ctr, 1u, __ATOMIC_RELAXED, __HIP_MEMORY_SCOPE_AGENT);
        while (__hip_atomic_load(ctr, __ATOMIC_RELAXED, __HIP_MEMORY_SCOPE_AGENT) < target)
            __builtin_amdgcn_s_sleep(2);
    }
    __syncthreads();
    __builtin_amdgcn_fence(__ATOMIC_ACQUIRE, "agent");   // buffer_inv: L1+L2
}

__global__ void zero_ctr(unsigned* c) { *c = 0u; }

// Persistent kernel, 256 blocks x 512 threads, 1 block/CU.
// Split-K outer-product mapping: lane l owns (col j, k-offset o); wave w owns
// batches 8w..8w+7 (8 fp32 accumulators/lane). Weight LDS reads are 64 unique
// contiguous float4 per wave-instr (frag index = q*64 + lane) -> 8x fewer LDS
// instructions than the broadcast scheme. Partials reduced with shfl_xor
// butterfly over the o bits.
__global__ __launch_bounds__(NTHR, 2) void gru_fused(
    const float* __restrict__ x,
    const float* __restrict__ Wz, const float* __restrict__ bz,
    const float* __restrict__ Wr, const float* __restrict__ br,
    const float* __restrict__ Wh, const float* __restrict__ bh,
    const float* __restrict__ Wo, const float* __restrict__ bo,
    float* __restrict__ out, float* __restrict__ ws)
{
    // LDS weight layouts (float4 "frag" = q*64 + (o*NJ + j), lane = o*NJ+j):
    //   gate  A: [q 48][o 8][j 8][c 4]   k = q*32  + o*4 + c   (8 cols)
    //   cand  B: [q 24][o 16][j 4][c 4]  k = q*64  + o*4 + c   (4 cols)
    //   out   O: [q 8][o 32][j 2][c 4]   k = q*128 + o*4 + c   (2 cols)
    __shared__ float wgA[8 * KK];    // 49152 B
    __shared__ float whB[4 * KK];    // 24576 B
    __shared__ float woO[2 * HH];    //  8192 B

    float* h  = ws;                  // [64][1024]
    float* hr = ws + 1 * 65536;      // h * r
    float* zb = ws + 2 * 65536;      // sigmoid(z)
    unsigned* ctr = (unsigned*)(ws + 3 * 65536);

    const int bid  = blockIdx.x;
    const int tid  = threadIdx.x;
    const int lane = tid & 63;
    const int w8   = (tid >> 6) * 8;     // this wave's batch base

    const bool is_r = (bid & 128) != 0;
    const float* Wg = is_r ? Wr : Wz;
    const int j0  = (bid & 127) * 8;
    const int j0h = bid * 4;
    const int j0o = bid * 2;

    // ---- stage weight slices to LDS in the [q][o][j][c] layout (once) ----
    for (int i = tid; i < KK * 8; i += NTHR) {
        int k = i >> 3, j = i & 7;
        wgA[(k >> 5) * 256 + ((k >> 2) & 7) * 32 + j * 4 + (k & 3)]
            = Wg[(size_t)k * HH + j0 + j];
    }
    for (int i = tid; i < KK * 4; i += NTHR) {
        int k = i >> 2, j = i & 3;
        whB[(k >> 6) * 256 + ((k >> 2) & 15) * 16 + j * 4 + (k & 3)]
            = Wh[(size_t)k * HH + j0h + j];
    }
    for (int i = tid; i < HH * 2; i += NTHR) {
        int k = i >> 1, j = i & 1;
        woO[(k >> 7) * 256 + ((k >> 2) & 31) * 8 + j * 4 + (k & 3)]
            = Wo[(size_t)k * OO + j0o + j];
    }

    // ---- init h = 0 ----
    {
        int g = bid * NTHR + tid;
        if (g < BB * HH) st_sys(&h[g], 0.0f);
    }

    // ---- per-thread fixed mappings ----
    const int oA = lane >> 3, jA = j0  + (lane & 7);
    const int oB = lane >> 2, jB = j0h + (lane & 3);
    const int oO = lane >> 1, jO = j0o + (lane & 1);
    const float biasA = is_r ? br[jA] : bz[jA];
    const float biasB = bh[jB];
    const float biasO = bo[jO];

    const float4* wA4 = (const float4*)wgA;
    const float4* wB4 = (const float4*)whB;
    const float4* wO4 = (const float4*)woO;

    unsigned tgt = GRID;
    gbar(ctr, tgt, tid);

    for (int t = 0; t < TT; ++t) {
        const float* xt = x + (size_t)t * BB * II;

        // ================= Phase A : gate (z or r) =================
        {
            float ph[8];
            if (is_r && lane < 8) {          // writers prefetch h for h*r
                #pragma unroll
                for (int i = 0; i < 8; ++i)
                    ph[i] = h[(size_t)(w8 + i) * HH + jA];
            }
            float acc[8];
            #pragma unroll
            for (int i = 0; i < 8; ++i) acc[i] = 0.f;

            const float* xbase = xt + (size_t)w8 * II + oA * 4;
            #pragma unroll
            for (int q = 0; q < 16; ++q) {           // k = 0..511 (x)
                float4 wv = wA4[q * 64 + lane];
                #pragma unroll
                for (int i = 0; i < 8; ++i) {
                    float4 av = *(const float4*)(xbase + i * II + q * 32);
                    acc[i] = fmaf(av.x, wv.x, acc[i]);
                    acc[i] = fmaf(av.y, wv.y, acc[i]);
                    acc[i] = fmaf(av.z, wv.z, acc[i]);
                    acc[i] = fmaf(av.w, wv.w, acc[i]);
                }
            }
            const float* hbase = h + (size_t)w8 * HH + oA * 4;
            #pragma unroll
            for (int q = 0; q < 32; ++q) {           // k = 512..1535 (h)
                float4 wv = wA4[(16 + q) * 64 + lane];
                #pragma unroll
                for (int i = 0; i < 8; ++i) {
                    float4 av = *(const float4*)(hbase + i * HH + q * 32);
                    acc[i] = fmaf(av.x, wv.x, acc[i]);
                    acc[i] = fmaf(av.y, wv.y, acc[i]);
                    acc[i] = fmaf(av.z, wv.z, acc[i]);
                    acc[i] = fmaf(av.w, wv.w, acc[i]);
                }
            }
            #pragma unroll
            for (int i = 0; i < 8; ++i) {            // reduce over o (bits 3..5)
                acc[i] += __shfl_xor(acc[i], 8);
                acc[i] += __shfl_xor(acc[i], 16);
                acc[i] += __shfl_xor(acc[i], 32);
            }
            if (lane < 8) {
                #pragma unroll
                for (int i = 0; i < 8; ++i) {
                    float val = sigmoidf_(biasA + acc[i]);
                    int idx = (w8 + i) * HH + jA;
                    if (is_r) st_sys(&hr[idx], ph[i] * val);
                    else      st_sys(&zb[idx], val);
                }
            }
        }

        // ================= out[t-1] = h @ Wo =================
        {
            float acc[8];
            #pragma unroll
            for (int i = 0; i < 8; ++i) acc[i] = 0.f;
            const float* hbase = h + (size_t)w8 * HH + oO * 4;
            #pragma unroll
            for (int q = 0; q < 8; ++q) {            // k = 0..1023
                float4 wv = wO4[q * 64 + lane];
                #pragma unroll
                for (int i = 0; i < 8; ++i) {
                    float4 av = *(const float4*)(hbase + i * HH + q * 128);
                    acc[i] = fmaf(av.x, wv.x, acc[i]);
                    acc[i] = fmaf(av.y, wv.y, acc[i]);
                    acc[i] = fmaf(av.z, wv.z, acc[i]);
                    acc[i] = fmaf(av.w, wv.w, acc[i]);
                }
            }
            #pragma unroll
            for (int i = 0; i < 8; ++i) {            // reduce over o (bits 1..5)
                acc[i] += __shfl_xor(acc[i], 2);
                acc[i] += __shfl_xor(acc[i], 4);
                acc[i] += __shfl_xor(acc[i], 8);
                acc[i] += __shfl_xor(acc[i], 16);
                acc[i] += __shfl_xor(acc[i], 32);
            }
            if (lane < 2 && t > 0) {
                #pragma unroll
                for (int i = 0; i < 8; ++i)
                    out[(size_t)(t - 1) * BB * OO + (w8 + i) * OO + jO]
                        = biasO + acc[i];
            }
        }

        tgt += GRID; gbar(ctr, tgt, tid);

        // ================= Phase B : candidate + h update =================
        {
            float pz[8], ph2[8];
            if (lane < 4) {                  // writers prefetch z and h_old
                #pragma unroll
                for (int i = 0; i < 8; ++i) {
                    pz[i]  = zb[(size_t)(w8 + i) * HH + jB];
                    ph2[i] = h [(size_t)(w8 + i) * HH + jB];
                }
            }
            float acc[8];
            #pragma unroll
            for (int i = 0; i < 8; ++i) acc[i] = 0.f;

            const float* xbase = xt + (size_t)w8 * II + oB * 4;
            #pragma unroll
            for (int q = 0; q < 8; ++q) {            // k = 0..511 (x)
                float4 wv = wB4[q * 64 + lane];
                #pragma unroll
                for (int i = 0; i < 8; ++i) {
                    float4 av = *(const float4*)(xbase + i * II + q * 64);
                    acc[i] = fmaf(av.x, wv.x, acc[i]);
                    acc[i] = fmaf(av.y, wv.y, acc[i]);
                    acc[i] = fmaf(av.z, wv.z, acc[i]);
                    acc[i] = fmaf(av.w, wv.w, acc[i]);
                }
            }
            const float* rbase = hr + (size_t)w8 * HH + oB * 4;
            #pragma unroll
            for (int q = 0; q < 16; ++q) {           // k = 512..1535 (h*r)
                float4 wv = wB4[(8 + q) * 64 + lane];
                #pragma unroll
                for (int i = 0; i < 8; ++i) {
                    float4 av = *(const float4*)(rbase + i * HH + q * 64);
                    acc[i] = fmaf(av.x, wv.x, acc[i]);
                    acc[i] = fmaf(av.y, wv.y, acc[i]);
                    acc[i] = fmaf(av.z, wv.z, acc[i]);
                    acc[i] = fmaf(av.w, wv.w, acc[i]);
                }
            }
            #pragma unroll
            for (int i = 0; i < 8; ++i) {            // reduce over o (bits 2..5)
                acc[i] += __shfl_xor(acc[i], 4);
                acc[i] += __shfl_xor(acc[i], 8);
                acc[i] += __shfl_xor(acc[i], 16);
                acc[i] += __shfl_xor(acc[i], 32);
            }
            if (lane < 4) {
                #pragma unroll
                for (int i = 0; i < 8; ++i) {
                    float cv = sigmoidf_(biasB + acc[i]);
                    float hn = pz[i] * ph2[i] + (1.0f - pz[i]) * cv;
                    st_sys(&h[(size_t)(w8 + i) * HH + jB], hn);
                }
            }
        }
        tgt += GRID; gbar(ctr, tgt, tid);
    }

    // ---- tail: out[T-1] = h_{T-1} @ Wo ----
    {
        float acc[8];
        #pragma unroll
        for (int i = 0; i < 8; ++i) acc[i] = 0.f;
        const float* hbase = h + (size_t)w8 * HH + oO * 4;
        #pragma unroll
        for (int q = 0; q < 8; ++q) {
            float4 wv = wO4[q * 64 + lane];
            #pragma unroll
            for (int i = 0; i < 8; ++i) {
                float4 av = *(const float4*)(hbase + i * HH + q * 128);
                acc[i] = fmaf(av.x, wv.x, acc[i]);
                acc[i] = fmaf(av.y, wv.y, acc[i]);
                acc[i] = fmaf(av.z, wv.z, acc[i]);
                acc[i] = fmaf(av.w, wv.w, acc[i]);
            }
        }
        #pragma unroll
        for (int i = 0; i < 8; ++i) {
            acc[i] += __shfl_xor(acc[i], 2);
            acc[i] += __shfl_xor(acc[i], 4);
            acc[i] += __shfl_xor(acc[i], 8);
            acc[i] += __shfl_xor(acc[i], 16);
            acc[i] += __shfl_xor(acc[i], 32);
        }
        if (lane < 2) {
            #pragma unroll
            for (int i = 0; i < 8; ++i)
                out[(size_t)(TT - 1) * BB * OO + (w8 + i) * OO + jO]
                    = biasO + acc[i];
        }
    }
}

extern "C" void kernel_launch(void* const* d_in, const int* in_sizes, int n_in,
                              void* d_out, int out_size, void* d_ws, size_t ws_size,
                              hipStream_t stream)
{
    (void)in_sizes; (void)n_in; (void)out_size; (void)ws_size;
    const float* x  = (const float*)d_in[0];
    const float* Wz = (const float*)d_in[1];
    const float* bz = (const float*)d_in[2];
    const float* Wr = (const float*)d_in[3];
    const float* br = (const float*)d_in[4];
    const float* Wh = (const float*)d_in[5];
    const float* bh = (const float*)d_in[6];
    const float* Wo = (const float*)d_in[7];
    const float* bo = (const float*)d_in[8];
    float* out = (float*)d_out;
    float* ws  = (float*)d_ws;   // 3*65536 floats state + barrier counter

    zero_ctr<<<1, 1, 0, stream>>>((unsigned*)(ws + 3 * 65536));

    void* args[] = { (void*)&x, (void*)&Wz, (void*)&bz, (void*)&Wr, (void*)&br,
                     (void*)&Wh, (void*)&bh, (void*)&Wo, (void*)&bo,
                     (void*)&out, (void*)&ws };
    hipLaunchCooperativeKernel(reinterpret_cast<void*>(gru_fused),
                               dim3(GRID), dim3(NTHR), args, 0, stream);
}

// Round 3
// 45817.465 us; speedup vs baseline: 4.1720x; 4.1720x over previous
//
#include <hip/hip_runtime.h>
#include <math.h>

#define TT 512
#define BB 64
#define II 512
#define HH 1024
#define OO 512
#define KK 1536   // I + H

#define GRID 256
#define NTHR 512

// LDS weight strides. WGS: 1540 % 32 == 4 -> gate/cand rows conflict-free.
// Wo stored with a 4-float skew per 256-float K-quarter: quarter q starts at
// q*260 -> banks 0/4/8/12 (+16 for col 1): conflict-free across okq threads.
#define WGS 1540
#define WOS2 1040   // 4 * 260

__device__ __forceinline__ float sigmoidf_(float v) {
    return 1.0f / (1.0f + __expf(-v));
}

// ---- write-through (LLC) store for mutable shared state ----
__device__ __forceinline__ void st_sys(float* p, float v) {
    asm volatile("global_store_dword %0, %1, off sc0 sc1"
                 :: "v"(p), "v"(v) : "memory");
}

// single-batch FMA (out-phase)
#define FMA4(av, wv) do { s0 = fmaf((av).x, (wv).x, s0); s1 = fmaf((av).y, (wv).y, s1); \
                          s2 = fmaf((av).z, (wv).z, s2); s3 = fmaf((av).w, (wv).w, s3); } while (0)
// dual-batch FMA: one weight fragment feeds two batch streams
#define FMA8(av, bv, wv) do { \
    s0 = fmaf((av).x, (wv).x, s0); s1 = fmaf((av).y, (wv).y, s1); \
    s2 = fmaf((av).z, (wv).z, s2); s3 = fmaf((av).w, (wv).w, s3); \
    u0 = fmaf((bv).x, (wv).x, u0); u1 = fmaf((bv).y, (wv).y, u1); \
    u2 = fmaf((bv).z, (wv).z, u2); u3 = fmaf((bv).w, (wv).w, u3); } while (0)

// Grid barrier: release (drain write-through stores) -> counter -> acquire
// (L1+L2 invalidate so cached loads see fresh LLC data).
__device__ __forceinline__ void gbar(unsigned* ctr, unsigned target, int tid)
{
    asm volatile("s_waitcnt vmcnt(0)" ::: "memory");
    __syncthreads();
    if (tid == 0) {
        __hip_atomic_fetch_add(ctr, 1u, __ATOMIC_RELAXED, __HIP_MEMORY_SCOPE_AGENT);
        while (__hip_atomic_load(ctr, __ATOMIC_RELAXED, __HIP_MEMORY_SCOPE_AGENT) < target)
            __builtin_amdgcn_s_sleep(2);
    }
    __syncthreads();
    __builtin_amdgcn_fence(__ATOMIC_ACQUIRE, "agent");   // buffer_inv: L1+L2
}

__global__ void zero_ctr(unsigned* c) { *c = 0u; }

// Persistent kernel, 256 blocks x 512 threads, 1 block/CU.
// R1 structure + dual-batch split-K: each thread owns 2 batches (b, b+32) per
// weight fragment; K split across thread groups (A: halves, B: quarters),
// partials reduced via red2[] in LDS. Weight-LDS instruction count drops
// ~2.2x while the GLOBAL access pattern stays identical to R1 (broadcast
// same-address groups + serial 16B row walk -> L1 hits + XCD-L2 dedupe).
__global__ __launch_bounds__(NTHR, 2) void gru_fused(
    const float* __restrict__ x,
    const float* __restrict__ Wz, const float* __restrict__ bz,
    const float* __restrict__ Wr, const float* __restrict__ br,
    const float* __restrict__ Wh, const float* __restrict__ bh,
    const float* __restrict__ Wo, const float* __restrict__ bo,
    float* __restrict__ out, float* __restrict__ ws)
{
    __shared__ float wg[8 * WGS];
    __shared__ float wh[4 * WGS];
    __shared__ float wo[2 * WOS2];
    __shared__ float red2[1024];

    float* h  = ws;                  // [64][1024]
    float* hr = ws + 1 * 65536;      // h * r
    float* zb = ws + 2 * 65536;      // sigmoid(z)
    unsigned* ctr = (unsigned*)(ws + 3 * 65536);

    const int bid = blockIdx.x;
    const int tid = threadIdx.x;

    // ---- stage weight slices to LDS (identical to R1) ----
    const bool is_r = (bid & 128) != 0;
    const float* Wg = is_r ? Wr : Wz;
    const int j0 = (bid & 127) * 8;
    for (int i = tid; i < KK * 8; i += NTHR) {
        int k = i >> 3, jj = i & 7;
        wg[jj * WGS + k] = Wg[(size_t)k * HH + j0 + jj];
    }
    const int j0h = bid * 4;
    for (int i = tid; i < KK * 4; i += NTHR) {
        int k = i >> 2, jj = i & 3;
        wh[jj * WGS + k] = Wh[(size_t)k * HH + j0h + jj];
    }
    const int j0o = bid * 2;
    for (int i = tid; i < HH * 2; i += NTHR) {   // skewed K-quarter layout
        int k = i >> 1, jj = i & 1;
        wo[jj * WOS2 + (k >> 8) * 260 + (k & 255)] = Wo[(size_t)k * OO + j0o + jj];
    }

    // ---- init h = 0 (ws is poisoned) ----
    {
        int g = bid * NTHR + tid;
        if (g < BB * HH) st_sys(&h[g], 0.0f);
    }

    // ---- per-thread fixed mappings ----
    // Phase A compute: kh = K-half, bAgA = batch-group (owns bAgA, bAgA+32), jjA = col
    const int khA  = tid >> 8;            // 0..1
    const int bAgA = (tid >> 3) & 31;     // 0..31
    const int jjA  = tid & 7;             // 0..7
    const float biasA = is_r ? br[j0 + jjA] : bz[j0 + jjA];

    // Phase B compute: kq = K-quarter, bAgB owns (bAgB, bAgB+32), bjB = col
    const int kqB  = tid >> 7;            // 0..3
    const int bAgB = (tid >> 2) & 31;     // 0..31
    const int bjB  = tid & 3;             // 0..3
    const float biasB = bh[j0h + (tid & 3)];

    // out-phase mapping (unchanged from R1)
    const int ocell = tid >> 2;
    const int okq   = tid & 3;
    const int ojo   = ocell & 1;
    const int ob    = ocell >> 1;
    const int jout  = j0o + ojo;
    const float obias = bo[jout];

    unsigned tgt = GRID;
    gbar(ctr, tgt, tid);

    for (int t = 0; t < TT; ++t) {
        const float* xt = x + (size_t)t * BB * II;

        // ================= Phase A : gate (z or r) =================
        {
            // writer-side prefetch: each thread owns cell (bW = tid>>3, jjA)
            float ph_own = 0.f;
            if (is_r) ph_own = h[(size_t)(tid >> 3) * HH + j0 + jjA];

            float s0=0.f,s1=0.f,s2=0.f,s3=0.f,u0=0.f,u1=0.f,u2=0.f,u3=0.f;
            const float4* wr4 = (const float4*)(wg + jjA * WGS);
            const int b0 = bAgA, b1 = bAgA + 32;
            if (khA == 0) {                          // k = 0..767
                const float4* xa = (const float4*)(xt + (size_t)b0 * II);
                const float4* xb = (const float4*)(xt + (size_t)b1 * II);
                #pragma unroll 16
                for (int q = 0; q < 128; ++q) {      // x part
                    float4 w = wr4[q];
                    float4 a = xa[q], b = xb[q];
                    FMA8(a, b, w);
                }
                const float4* ha = (const float4*)(h + (size_t)b0 * HH);
                const float4* hb = (const float4*)(h + (size_t)b1 * HH);
                #pragma unroll 16
                for (int q = 0; q < 64; ++q) {       // h cols 0..255
                    float4 w = wr4[128 + q];
                    float4 a = ha[q], b = hb[q];
                    FMA8(a, b, w);
                }
            } else {                                  // k = 768..1535
                const float4* ha = (const float4*)(h + (size_t)b0 * HH + 256);
                const float4* hb = (const float4*)(h + (size_t)b1 * HH + 256);
                #pragma unroll 16
                for (int q = 0; q < 192; ++q) {      // h cols 256..1023
                    float4 w = wr4[192 + q];
                    float4 a = ha[q], b = hb[q];
                    FMA8(a, b, w);
                }
            }
            red2[khA * 512 + bAgA * 16 + jjA]     = (s0 + s1) + (s2 + s3);
            red2[khA * 512 + bAgA * 16 + 8 + jjA] = (u0 + u1) + (u2 + u3);
            __syncthreads();
            {
                const int bW = tid >> 3;
                const int off = (bW & 31) * 16 + (bW >> 5) * 8 + jjA;
                float gv  = red2[off] + red2[512 + off];
                float val = sigmoidf_(biasA + gv);
                int idx = bW * HH + j0 + jjA;
                if (is_r) st_sys(&hr[idx], ph_own * val);
                else      st_sys(&zb[idx], val);
            }
            __syncthreads();   // red2 reuse guard
        }

        // ================= out[t-1] = h @ Wo (R1 pattern) =================
        {
            const float4* oh4 = (const float4*)(h + ob * HH + okq * 256);
            const float4* ow4 = (const float4*)(wo + ojo * WOS2 + okq * 260);
            float s0=0.f,s1=0.f,s2=0.f,s3=0.f;
            #pragma unroll 16
            for (int q = 0; q < 64; ++q) {
                float4 a = oh4[q];
                float4 w = ow4[q];
                FMA4(a, w);
            }
            red2[tid] = (s0 + s1) + (s2 + s3);
            __syncthreads();
            if (okq == 0 && t > 0) {
                float tot = obias + ((red2[tid] + red2[tid + 1]) +
                                     (red2[tid + 2] + red2[tid + 3]));
                out[(size_t)(t - 1) * BB * OO + ob * OO + jout] = tot;
            }
        }

        tgt += GRID; gbar(ctr, tgt, tid);

        // ================= Phase B : candidate + h update =================
        {
            // writer-side prefetch (cells owned by tid<256)
            float pz = 0.f, ph2 = 0.f;
            if (tid < 256) {
                int idx = (tid >> 2) * HH + j0h + (tid & 3);
                pz  = zb[idx];
                ph2 = h[idx];
            }

            float s0=0.f,s1=0.f,s2=0.f,s3=0.f,u0=0.f,u1=0.f,u2=0.f,u3=0.f;
            const float4* wr4 = (const float4*)(wh + bjB * WGS);
            const int c0 = bAgB, c1 = bAgB + 32;
            if (kqB == 0) {                           // x f4 0..95
                const float4* xa = (const float4*)(xt + (size_t)c0 * II);
                const float4* xb = (const float4*)(xt + (size_t)c1 * II);
                #pragma unroll 16
                for (int q = 0; q < 96; ++q) {
                    float4 w = wr4[q];
                    float4 a = xa[q], b = xb[q];
                    FMA8(a, b, w);
                }
            } else if (kqB == 1) {                    // x f4 96..127 + hr f4 0..63
                const float4* xa = (const float4*)(xt + (size_t)c0 * II);
                const float4* xb = (const float4*)(xt + (size_t)c1 * II);
                #pragma unroll 16
                for (int q = 96; q < 128; ++q) {
                    float4 w = wr4[q];
                    float4 a = xa[q], b = xb[q];
                    FMA8(a, b, w);
                }
                const float4* ra = (const float4*)(hr + (size_t)c0 * HH);
                const float4* rb = (const float4*)(hr + (size_t)c1 * HH);
                #pragma unroll 16
                for (int q = 0; q < 64; ++q) {
                    float4 w = wr4[128 + q];
                    float4 a = ra[q], b = rb[q];
                    FMA8(a, b, w);
                }
            } else if (kqB == 2) {                    // hr f4 64..159
                const float4* ra = (const float4*)(hr + (size_t)c0 * HH);
                const float4* rb = (const float4*)(hr + (size_t)c1 * HH);
                #pragma unroll 16
                for (int q = 0; q < 96; ++q) {
                    float4 w = wr4[192 + q];
                    float4 a = ra[64 + q], b = rb[64 + q];
                    FMA8(a, b, w);
                }
            } else {                                  // hr f4 160..255
                const float4* ra = (const float4*)(hr + (size_t)c0 * HH);
                const float4* rb = (const float4*)(hr + (size_t)c1 * HH);
                #pragma unroll 16
                for (int q = 0; q < 96; ++q) {
                    float4 w = wr4[288 + q];
                    float4 a = ra[160 + q], b = rb[160 + q];
                    FMA8(a, b, w);
                }
            }
            {
                int off = bAgB * 8 + bjB;
                red2[kqB * 256 + off]     = (s0 + s1) + (s2 + s3);
                red2[kqB * 256 + off + 4] = (u0 + u1) + (u2 + u3);
            }
            __syncthreads();
            if (tid < 256) {
                int b  = tid >> 2, bj = tid & 3;
                int o2 = (b & 31) * 8 + (b >> 5) * 4 + bj;
                float part = (red2[o2] + red2[256 + o2]) +
                             (red2[512 + o2] + red2[768 + o2]);
                float cv = sigmoidf_(biasB + part);
                float hn = pz * ph2 + (1.0f - pz) * cv;
                st_sys(&h[b * HH + j0h + bj], hn);
            }
        }
        tgt += GRID; gbar(ctr, tgt, tid);
    }

    // ---- tail: out[T-1] = h_{T-1} @ Wo ----
    {
        const float4* oh4 = (const float4*)(h + ob * HH + okq * 256);
        const float4* ow4 = (const float4*)(wo + ojo * WOS2 + okq * 260);
        float s0=0.f,s1=0.f,s2=0.f,s3=0.f;
        #pragma unroll 16
        for (int q = 0; q < 64; ++q) {
            float4 a = oh4[q];
            float4 w = ow4[q];
            FMA4(a, w);
        }
        red2[tid] = (s0 + s1) + (s2 + s3);
        __syncthreads();
        if (okq == 0) {
            float tot = obias + ((red2[tid] + red2[tid + 1]) +
                                 (red2[tid + 2] + red2[tid + 3]));
            out[(size_t)(TT - 1) * BB * OO + ob * OO + jout] = tot;
        }
    }
}

extern "C" void kernel_launch(void* const* d_in, const int* in_sizes, int n_in,
                              void* d_out, int out_size, void* d_ws, size_t ws_size,
                              hipStream_t stream)
{
    (void)in_sizes; (void)n_in; (void)out_size; (void)ws_size;
    const float* x  = (const float*)d_in[0];
    const float* Wz = (const float*)d_in[1];
    const float* bz = (const float*)d_in[2];
    const float* Wr = (const float*)d_in[3];
    const float* br = (const float*)d_in[4];
    const float* Wh = (const float*)d_in[5];
    const float* bh = (const float*)d_in[6];
    const float* Wo = (const float*)d_in[7];
    const float* bo = (const float*)d_in[8];
    float* out = (float*)d_out;
    float* ws  = (float*)d_ws;   // 3*65536 floats state + barrier counter

    zero_ctr<<<1, 1, 0, stream>>>((unsigned*)(ws + 3 * 65536));

    void* args[] = { (void*)&x, (void*)&Wz, (void*)&bz, (void*)&Wr, (void*)&br,
                     (void*)&Wh, (void*)&bh, (void*)&Wo, (void*)&bo,
                     (void*)&out, (void*)&ws };
    hipLaunchCooperativeKernel(reinterpret_cast<void*>(gru_fused),
                               dim3(GRID), dim3(NTHR), args, 0, stream);
}

// Round 4
// 29053.021 us; speedup vs baseline: 6.5794x; 1.5770x over previous
//
#include <hip/hip_runtime.h>
#include <math.h>

#define TT 512
#define BB 64
#define II 512
#define HH 1024
#define OO 512
#define KK 1536   // I + H

#define GRID 256
#define NTHR 512

__device__ __forceinline__ float sigmoidf_(float v) {
    return 1.0f / (1.0f + __expf(-v));
}

// ---- write-through (LLC) store for mutable shared state ----
__device__ __forceinline__ void st_sys(float* p, float v) {
    asm volatile("global_store_dword %0, %1, off sc0 sc1"
                 :: "v"(p), "v"(v) : "memory");
}

#define DOT4(accv, av, wv) do { \
    (accv) = fmaf((av).x, (wv).x, (accv)); \
    (accv) = fmaf((av).y, (wv).y, (accv)); \
    (accv) = fmaf((av).z, (wv).z, (accv)); \
    (accv) = fmaf((av).w, (wv).w, (accv)); } while (0)

// Hierarchical grid barrier: 8 group counters (32 blocks each, 128B apart)
// + 1 root. Release: drain write-through stores. Acquire: L1+L2 invalidate
// so plain cached loads see fresh LLC data. Root grows by 8 per barrier.
__device__ __forceinline__ void gbar(unsigned* cb, unsigned target8, int tid, int grp)
{
    asm volatile("s_waitcnt vmcnt(0)" ::: "memory");
    __syncthreads();
    if (tid == 0) {
        unsigned old = __hip_atomic_fetch_add(&cb[grp * 32], 1u,
                           __ATOMIC_RELAXED, __HIP_MEMORY_SCOPE_AGENT);
        if ((old & 31u) == 31u)
            __hip_atomic_fetch_add(&cb[256], 1u,
                __ATOMIC_RELAXED, __HIP_MEMORY_SCOPE_AGENT);
        while (__hip_atomic_load(&cb[256], __ATOMIC_RELAXED,
                   __HIP_MEMORY_SCOPE_AGENT) < target8)
            __builtin_amdgcn_s_sleep(1);
    }
    __syncthreads();
    __builtin_amdgcn_fence(__ATOMIC_ACQUIRE, "agent");   // buffer_inv: L1+L2
}

__global__ void zero_ctr(unsigned* c) {
    for (int i = 0; i < 8; ++i) c[i * 32] = 0u;
    c[256] = 0u;
}

// Persistent kernel, 256 blocks x 512 threads, 1 block/CU.
// Register-tiled split-K: thread = (bg 0..15, ko 0..31). Each thread owns a
// 4-batch x 8-col acc tile and k-quads kq = ko + 32u (interleaved K-slice).
// Activations stream from GLOBAL per-lane-unique fully coalesced (each f4
// read exactly once per CU); weights stream from LDS per-lane-unique
// (conflict-free, 4x register reuse across batches). K-partials reduced by
// shfl_xor butterfly within each 32-lane half-wave; one cell finalized per
// lane via static cndmask select.
__global__ __launch_bounds__(NTHR, 2) void gru_fused(
    const float* __restrict__ x,
    const float* __restrict__ Wz, const float* __restrict__ bz,
    const float* __restrict__ Wr, const float* __restrict__ br,
    const float* __restrict__ Wh, const float* __restrict__ bh,
    const float* __restrict__ Wo, const float* __restrict__ bo,
    float* __restrict__ out, float* __restrict__ ws)
{
    // LDS weights, flat [j][k] (k-major per column). Reads are per-lane
    // contiguous f4 (idx16 = j*384 + ko + 32u) -> conflict-free.
    __shared__ float wgA[8 * KK];    // 48 KB : gate (z or r), 8 cols
    __shared__ float whB[4 * KK];    // 24 KB : candidate, 4 cols
    __shared__ float woO[2 * HH];    //  8 KB : out, 2 cols

    float* h  = ws;                  // [64][1024]
    float* hr = ws + 1 * 65536;      // h * r
    float* zb = ws + 2 * 65536;      // sigmoid(z)
    unsigned* cb = (unsigned*)(ws + 3 * 65536);   // barrier counters

    const int bid = blockIdx.x;
    const int tid = threadIdx.x;
    const int grp = bid >> 5;

    const bool is_r = (bid & 128) != 0;
    const float* Wg = is_r ? Wr : Wz;
    const int j0  = (bid & 127) * 8;
    const int j0h = bid * 4;
    const int j0o = bid * 2;

    // ---- stage weight slices to LDS, [j][k] flat (once) ----
    for (int i = tid; i < KK * 8; i += NTHR)
        wgA[(i & 7) * KK + (i >> 3)] = Wg[(size_t)(i >> 3) * HH + j0 + (i & 7)];
    for (int i = tid; i < KK * 4; i += NTHR)
        whB[(i & 3) * KK + (i >> 2)] = Wh[(size_t)(i >> 2) * HH + j0h + (i & 3)];
    for (int i = tid; i < HH * 2; i += NTHR)
        woO[(i & 1) * HH + (i >> 1)] = Wo[(size_t)(i >> 1) * OO + j0o + (i & 1)];

    // ---- init h = 0 (ws is poisoned) ----
    {
        int g = bid * NTHR + tid;
        if (g < BB * HH) st_sys(&h[g], 0.0f);
    }

    // ---- per-thread fixed mappings ----
    const int ko = tid & 31;          // k-slice
    const int bg = tid >> 5;          // batch group (4 batches)
    const int b0 = bg * 4;

    // finalize-cell mappings (one cell per lane per phase)
    const int ciA = ko >> 3, cjA = ko & 7;           // phase A (all 32 lanes)
    const int bA = b0 + ciA, jA = j0 + cjA;
    const float biasA = is_r ? br[jA] : bz[jA];

    const int ciB = ko >> 2, cjB = ko & 3;           // phase B (lanes ko<16)
    const int bB = b0 + ciB, jB = j0h + cjB;
    const float biasB = bh[jB];

    const int ciO = ko >> 1, cjO = ko & 1;           // out (lanes ko<8)
    const int bO = b0 + ciO, jO = j0o + cjO;
    const float biasO = bo[jO];

    const float4* wg4 = (const float4*)wgA;
    const float4* wh4 = (const float4*)whB;
    const float4* wo4 = (const float4*)woO;

    unsigned tgt = 8;
    gbar(cb, tgt, tid, grp);

    for (int t = 0; t < TT; ++t) {
        const float* xt = x + (size_t)t * BB * II;

        const float4* xp0 = (const float4*)(xt + (size_t)(b0 + 0) * II);
        const float4* xp1 = (const float4*)(xt + (size_t)(b0 + 1) * II);
        const float4* xp2 = (const float4*)(xt + (size_t)(b0 + 2) * II);
        const float4* xp3 = (const float4*)(xt + (size_t)(b0 + 3) * II);
        const float4* hp0 = (const float4*)(h + (size_t)(b0 + 0) * HH);
        const float4* hp1 = (const float4*)(h + (size_t)(b0 + 1) * HH);
        const float4* hp2 = (const float4*)(h + (size_t)(b0 + 2) * HH);
        const float4* hp3 = (const float4*)(h + (size_t)(b0 + 3) * HH);

        // ================= Phase A : gate (z or r), 8 cols =================
        {
            const size_t iA = (size_t)bA * HH + jA;
            float hpre = 0.f;
            if (is_r) hpre = h[iA];          // prefetch h for hr product

            float acc[4][8];
            #pragma unroll
            for (int i = 0; i < 4; ++i)
                #pragma unroll
                for (int j = 0; j < 8; ++j) acc[i][j] = 0.f;

            #pragma unroll
            for (int u = 0; u < 12; ++u) {
                const int kq = ko + 32 * u;
                float4 av[4];
                if (u < 4) {
                    av[0] = xp0[kq]; av[1] = xp1[kq];
                    av[2] = xp2[kq]; av[3] = xp3[kq];
                } else {
                    av[0] = hp0[kq - 128]; av[1] = hp1[kq - 128];
                    av[2] = hp2[kq - 128]; av[3] = hp3[kq - 128];
                }
                #pragma unroll
                for (int jh = 0; jh < 2; ++jh) {
                    float4 wv[4];
                    #pragma unroll
                    for (int jj = 0; jj < 4; ++jj)
                        wv[jj] = wg4[(jh * 4 + jj) * 384 + kq];
                    #pragma unroll
                    for (int i = 0; i < 4; ++i)
                        #pragma unroll
                        for (int jj = 0; jj < 4; ++jj)
                            DOT4(acc[i][jh * 4 + jj], av[i], wv[jj]);
                }
            }
            // butterfly reduce over ko (stays within each 32-lane half)
            float cellA = 0.f;
            #pragma unroll
            for (int i = 0; i < 4; ++i)
                #pragma unroll
                for (int j = 0; j < 8; ++j) {
                    float v = acc[i][j];
                    v += __shfl_xor(v, 1);
                    v += __shfl_xor(v, 2);
                    v += __shfl_xor(v, 4);
                    v += __shfl_xor(v, 8);
                    v += __shfl_xor(v, 16);
                    if (ciA == i && cjA == j) cellA = v;
                }
            float val = sigmoidf_(biasA + cellA);
            if (is_r) st_sys(&hr[iA], hpre * val);
            else      st_sys(&zb[iA], val);
        }

        // ================= out[t-1] = h @ Wo (h is L1-warm) =================
        {
            float acc[4][2];
            #pragma unroll
            for (int i = 0; i < 4; ++i) { acc[i][0] = 0.f; acc[i][1] = 0.f; }

            #pragma unroll
            for (int u = 0; u < 8; ++u) {
                const int kq = ko + 32 * u;
                float4 av[4];
                av[0] = hp0[kq]; av[1] = hp1[kq];
                av[2] = hp2[kq]; av[3] = hp3[kq];
                float4 w0 = wo4[kq];
                float4 w1 = wo4[256 + kq];
                #pragma unroll
                for (int i = 0; i < 4; ++i) {
                    DOT4(acc[i][0], av[i], w0);
                    DOT4(acc[i][1], av[i], w1);
                }
            }
            float cellO = 0.f;
            #pragma unroll
            for (int i = 0; i < 4; ++i)
                #pragma unroll
                for (int j = 0; j < 2; ++j) {
                    float v = acc[i][j];
                    v += __shfl_xor(v, 1);
                    v += __shfl_xor(v, 2);
                    v += __shfl_xor(v, 4);
                    v += __shfl_xor(v, 8);
                    v += __shfl_xor(v, 16);
                    if (ciO == i && cjO == j) cellO = v;
                }
            if (ko < 8 && t > 0)
                out[(size_t)(t - 1) * BB * OO + (size_t)bO * OO + jO]
                    = biasO + cellO;
        }

        tgt += 8; gbar(cb, tgt, tid, grp);

        // ================= Phase B : candidate + h update =================
        {
            const size_t iB = (size_t)bB * HH + jB;
            float zpre = 0.f, hpre2 = 0.f;
            if (ko < 16) { zpre = zb[iB]; hpre2 = h[iB]; }

            const float4* rp0 = (const float4*)(hr + (size_t)(b0 + 0) * HH);
            const float4* rp1 = (const float4*)(hr + (size_t)(b0 + 1) * HH);
            const float4* rp2 = (const float4*)(hr + (size_t)(b0 + 2) * HH);
            const float4* rp3 = (const float4*)(hr + (size_t)(b0 + 3) * HH);

            float acc[4][4];
            #pragma unroll
            for (int i = 0; i < 4; ++i)
                #pragma unroll
                for (int j = 0; j < 4; ++j) acc[i][j] = 0.f;

            #pragma unroll
            for (int u = 0; u < 12; ++u) {
                const int kq = ko + 32 * u;
                float4 av[4];
                if (u < 4) {
                    av[0] = xp0[kq]; av[1] = xp1[kq];
                    av[2] = xp2[kq]; av[3] = xp3[kq];
                } else {
                    av[0] = rp0[kq - 128]; av[1] = rp1[kq - 128];
                    av[2] = rp2[kq - 128]; av[3] = rp3[kq - 128];
                }
                float4 wv[4];
                #pragma unroll
                for (int jj = 0; jj < 4; ++jj)
                    wv[jj] = wh4[jj * 384 + kq];
                #pragma unroll
                for (int i = 0; i < 4; ++i)
                    #pragma unroll
                    for (int jj = 0; jj < 4; ++jj)
                        DOT4(acc[i][jj], av[i], wv[jj]);
            }
            float cellB = 0.f;
            #pragma unroll
            for (int i = 0; i < 4; ++i)
                #pragma unroll
                for (int j = 0; j < 4; ++j) {
                    float v = acc[i][j];
                    v += __shfl_xor(v, 1);
                    v += __shfl_xor(v, 2);
                    v += __shfl_xor(v, 4);
                    v += __shfl_xor(v, 8);
                    v += __shfl_xor(v, 16);
                    if (ciB == i && cjB == j) cellB = v;
                }
            if (ko < 16) {
                float cv = sigmoidf_(biasB + cellB);
                st_sys(&h[iB], zpre * hpre2 + (1.0f - zpre) * cv);
            }
        }
        tgt += 8; gbar(cb, tgt, tid, grp);
    }

    // ---- tail: out[T-1] = h_{T-1} @ Wo ----
    {
        const float4* hp0 = (const float4*)(h + (size_t)(b0 + 0) * HH);
        const float4* hp1 = (const float4*)(h + (size_t)(b0 + 1) * HH);
        const float4* hp2 = (const float4*)(h + (size_t)(b0 + 2) * HH);
        const float4* hp3 = (const float4*)(h + (size_t)(b0 + 3) * HH);
        float acc[4][2];
        #pragma unroll
        for (int i = 0; i < 4; ++i) { acc[i][0] = 0.f; acc[i][1] = 0.f; }
        #pragma unroll
        for (int u = 0; u < 8; ++u) {
            const int kq = ko + 32 * u;
            float4 av[4];
            av[0] = hp0[kq]; av[1] = hp1[kq];
            av[2] = hp2[kq]; av[3] = hp3[kq];
            float4 w0 = wo4[kq];
            float4 w1 = wo4[256 + kq];
            #pragma unroll
            for (int i = 0; i < 4; ++i) {
                DOT4(acc[i][0], av[i], w0);
                DOT4(acc[i][1], av[i], w1);
            }
        }
        float cellO = 0.f;
        #pragma unroll
        for (int i = 0; i < 4; ++i)
            #pragma unroll
            for (int j = 0; j < 2; ++j) {
                float v = acc[i][j];
                v += __shfl_xor(v, 1);
                v += __shfl_xor(v, 2);
                v += __shfl_xor(v, 4);
                v += __shfl_xor(v, 8);
                v += __shfl_xor(v, 16);
                if (ciO == i && cjO == j) cellO = v;
            }
        if (ko < 8)
            out[(size_t)(TT - 1) * BB * OO + (size_t)bO * OO + jO]
                = biasO + cellO;
    }
}

extern "C" void kernel_launch(void* const* d_in, const int* in_sizes, int n_in,
                              void* d_out, int out_size, void* d_ws, size_t ws_size,
                              hipStream_t stream)
{
    (void)in_sizes; (void)n_in; (void)out_size; (void)ws_size;
    const float* x  = (const float*)d_in[0];
    const float* Wz = (const float*)d_in[1];
    const float* bz = (const float*)d_in[2];
    const float* Wr = (const float*)d_in[3];
    const float* br = (const float*)d_in[4];
    const float* Wh = (const float*)d_in[5];
    const float* bh = (const float*)d_in[6];
    const float* Wo = (const float*)d_in[7];
    const float* bo = (const float*)d_in[8];
    float* out = (float*)d_out;
    float* ws  = (float*)d_ws;   // 3*65536 floats state + barrier counters

    zero_ctr<<<1, 1, 0, stream>>>((unsigned*)(ws + 3 * 65536));

    void* args[] = { (void*)&x, (void*)&Wz, (void*)&bz, (void*)&Wr, (void*)&br,
                     (void*)&Wh, (void*)&bh, (void*)&Wo, (void*)&bo,
                     (void*)&out, (void*)&ws };
    hipLaunchCooperativeKernel(reinterpret_cast<void*>(gru_fused),
                               dim3(GRID), dim3(NTHR), args, 0, stream);
}